// Round 1
// baseline (106.728 us; speedup 1.0000x reference)
//
#include <hip/hip_runtime.h>

// Problem constants (from reference): D=32, H=64, O=1, T=1024, M=8, N=32768
#define DD 32
#define HH 64
#define TT 1024
#define MM 8
#define NN 32768
#define SS 2177              // H*D + H + O*H + O
#define SP 2180              // padded row stride (floats) -> 16B-aligned rows

// states[t][s] = base[s] + bias[s] + sum_m meta_w[s][m] * mesa[m][t]
__global__ __launch_bounds__(256) void states_kernel(
    const float* __restrict__ mesa,   // (M, T)
    const float* __restrict__ metaw,  // (S, M)
    const float* __restrict__ metab,  // (S,)
    const float* __restrict__ base,   // (S,)
    float* __restrict__ states)       // (T, SP)
{
    int s = blockIdx.x * 256 + threadIdx.x;
    int t = blockIdx.y;
    if (s >= SS) return;
    const float4* mw = (const float4*)(metaw + s * MM);
    float4 a = mw[0], b = mw[1];
    float acc = base[s] + metab[s];
    acc = fmaf(a.x, mesa[0 * TT + t], acc);
    acc = fmaf(a.y, mesa[1 * TT + t], acc);
    acc = fmaf(a.z, mesa[2 * TT + t], acc);
    acc = fmaf(a.w, mesa[3 * TT + t], acc);
    acc = fmaf(b.x, mesa[4 * TT + t], acc);
    acc = fmaf(b.y, mesa[5 * TT + t], acc);
    acc = fmaf(b.z, mesa[6 * TT + t], acc);
    acc = fmaf(b.w, mesa[7 * TT + t], acc);
    states[(size_t)t * SP + s] = acc;
}

// One wave (64 lanes) per sample. Lane j computes h[j] = relu(x . w1[t][j] + b1[t][j]),
// then wave-reduces h . w2[t] for the single output.
__global__ __launch_bounds__(256) void mlp_kernel(
    const float* __restrict__ x,       // (N, D)
    const int*   __restrict__ ticker,  // (N,)
    const float* __restrict__ states,  // (T, SP)
    float* __restrict__ out)           // (N, 1)
{
    int wave = threadIdx.x >> 6;
    int lane = threadIdx.x & 63;
    int n = blockIdx.x * 4 + wave;

    int t = ticker[n];
    const float* row = states + (size_t)t * SP;

    // broadcast source: lanes 0..31 hold x[n][0..31]
    float xv = (lane < DD) ? x[n * DD + lane] : 0.0f;

    // lane j's w1 row slice: 32 contiguous floats = 8 x float4 (16B aligned via SP pad)
    const float4* wp = (const float4*)(row + lane * DD);
    float h = 0.0f;
#pragma unroll
    for (int q = 0; q < 8; ++q) {
        float4 w = wp[q];
        h = fmaf(__shfl(xv, 4 * q + 0, 64), w.x, h);
        h = fmaf(__shfl(xv, 4 * q + 1, 64), w.y, h);
        h = fmaf(__shfl(xv, 4 * q + 2, 64), w.z, h);
        h = fmaf(__shfl(xv, 4 * q + 3, 64), w.w, h);
    }
    h += row[HH * DD + lane];          // b1
    h = fmaxf(h, 0.0f);                // relu

    float p = h * row[HH * DD + HH + lane];  // * w2
#pragma unroll
    for (int off = 32; off >= 1; off >>= 1)
        p += __shfl_down(p, off, 64);

    if (lane == 0)
        out[n] = p + row[HH * DD + HH + HH];  // + b2
}

extern "C" void kernel_launch(void* const* d_in, const int* in_sizes, int n_in,
                              void* d_out, int out_size, void* d_ws, size_t ws_size,
                              hipStream_t stream) {
    const float* x      = (const float*)d_in[0];
    const int*   ticker = (const int*)  d_in[1];
    const float* mesa   = (const float*)d_in[2];
    const float* metaw  = (const float*)d_in[3];
    const float* metab  = (const float*)d_in[4];
    const float* base   = (const float*)d_in[5];
    float* out    = (float*)d_out;
    float* states = (float*)d_ws;   // needs T*SP*4 = ~8.93 MB

    dim3 g1((SS + 255) / 256, TT);  // 9 x 1024 blocks
    states_kernel<<<g1, 256, 0, stream>>>(mesa, metaw, metab, base, states);

    mlp_kernel<<<NN / 4, 256, 0, stream>>>(x, ticker, states, out);
}